// Round 3
// baseline (667.574 us; speedup 1.0000x reference)
//
#include <hip/hip_runtime.h>
#include <hip/hip_fp16.h>

#define N_NODES 50000
#define N_EDGES 800000
#define N_OBS   4
#define HID     64
#define K_HOPS  5
#define ROW     (N_OBS * HID)   // 256 elements per node
#define NSCAN_BLKS ((N_NODES + 1023) / 1024)   // 49

// ---------------------------------------------------------------- zero
__global__ void zero_kernel(int* __restrict__ p, int n) {
    int i = blockIdx.x * blockDim.x + threadIdx.x;
    if (i < n) p[i] = 0;
}

// ---------------------------------------------------------------- histogram of dst
__global__ void hist_kernel(const int* __restrict__ dst, int* __restrict__ cnt) {
    int e = blockIdx.x * blockDim.x + threadIdx.x;
    if (e < N_EDGES) atomicAdd(&cnt[dst[e]], 1);
}

// ---------------------------------------------------------------- scan pass 1: per-block sums
__global__ __launch_bounds__(1024) void scan1_kernel(const int* __restrict__ counts,
                                                     int* __restrict__ bsum) {
    __shared__ int wsum[16];
    const int t = threadIdx.x, lane = t & 63, wid = t >> 6;
    int i = blockIdx.x * 1024 + t;
    int x = (i < N_NODES) ? counts[i] : 0;
    #pragma unroll
    for (int off = 32; off > 0; off >>= 1) x += __shfl_xor(x, off);
    if (lane == 0) wsum[wid] = x;
    __syncthreads();
    if (t == 0) {
        int s = 0;
        #pragma unroll
        for (int j = 0; j < 16; ++j) s += wsum[j];
        bsum[blockIdx.x] = s;
    }
}

// ---------------------------------------------------------------- scan pass 2: exclusive scan of block sums (1 wave)
__global__ void scan2_kernel(int* __restrict__ bsum) {
    const int t = threadIdx.x;   // 64 threads
    int v = (t < NSCAN_BLKS) ? bsum[t] : 0;
    int x = v;
    #pragma unroll
    for (int off = 1; off < 64; off <<= 1) {
        int y = __shfl_up(x, off);
        if (t >= off) x += y;
    }
    if (t < NSCAN_BLKS) bsum[t] = x - v;   // exclusive
}

// ---------------------------------------------------------------- scan pass 3: full offsets + cursor
__global__ __launch_bounds__(1024) void scan3_kernel(const int* __restrict__ counts,
                                                     const int* __restrict__ bsum,
                                                     int* __restrict__ offsets,
                                                     int* __restrict__ cursor) {
    __shared__ int wsum[16];
    __shared__ int wpre[16];
    const int t = threadIdx.x, lane = t & 63, wid = t >> 6;
    int i = blockIdx.x * 1024 + t;
    int v = (i < N_NODES) ? counts[i] : 0;
    int x = v;
    #pragma unroll
    for (int off = 1; off < 64; off <<= 1) {
        int y = __shfl_up(x, off);
        if (lane >= off) x += y;
    }
    if (lane == 63) wsum[wid] = x;
    __syncthreads();
    if (t < 16) {
        int p = 0;
        for (int j = 0; j < t; ++j) p += wsum[j];
        wpre[t] = p;
    }
    __syncthreads();
    int base = bsum[blockIdx.x];
    int incl = base + x + wpre[wid];
    if (i < N_NODES) {
        offsets[i + 1] = incl;
        cursor[i]      = incl - v;
    }
    if (i == 0) offsets[0] = 0;
}

// ---------------------------------------------------------------- scatter edges into CSR order (packed {src*ROW, w})
__global__ void scatter_kernel(const int* __restrict__ src, const int* __restrict__ dst,
                               const float* __restrict__ w, int* __restrict__ cursor,
                               int2* __restrict__ sedg) {
    int e = blockIdx.x * blockDim.x + threadIdx.x;
    if (e < N_EDGES) {
        int d = dst[e];
        int p = atomicAdd(&cursor[d], 1);
        sedg[p] = make_int2(src[e] * ROW, __float_as_int(w[e]));
    }
}

// ---------------------------------------------------------------- lift: X[n,o,h] = f16(nodes[n,o]*Wl[h] + bl[h])
__global__ void lift_kernel(const float* __restrict__ nodes, const float* __restrict__ Wl,
                            const float* __restrict__ bl, __half* __restrict__ X) {
    int i = blockIdx.x * blockDim.x + threadIdx.x;
    const int total = N_NODES * ROW / 4;
    if (i >= total) return;
    int h4 = i & 15;
    int no = i >> 4;
    float s = nodes[no];
    float4 wl = ((const float4*)Wl)[h4];
    float4 b  = ((const float4*)bl)[h4];
    __half2 lo = __float22half2_rn(make_float2(s * wl.x + b.x, s * wl.y + b.y));
    __half2 hi = __float22half2_rn(make_float2(s * wl.z + b.z, s * wl.w + b.w));
    float2 st;
    *(__half2*)&st.x = lo;
    *(__half2*)&st.y = hi;
    ((float2*)X)[i] = st;
}

// ---------------------------------------------------------------- fused hop, barrier-free:
// one wave per dst node. Gather: 2 edges per load inst (half-wave each, 16B/lane),
// edge list preloaded+shfl-broadcast. Then per-wave 4x64 @ 64x64 GEMM (W via L1).
#define ACC8(r, w)                                              \
    {                                                           \
        __half2* _h = (__half2*)&(r);                           \
        float2 _f0 = __half22float2(_h[0]);                     \
        float2 _f1 = __half22float2(_h[1]);                     \
        float2 _f2 = __half22float2(_h[2]);                     \
        float2 _f3 = __half22float2(_h[3]);                     \
        acc[0] += (w) * _f0.x; acc[1] += (w) * _f0.y;           \
        acc[2] += (w) * _f1.x; acc[3] += (w) * _f1.y;           \
        acc[4] += (w) * _f2.x; acc[5] += (w) * _f2.y;           \
        acc[6] += (w) * _f3.x; acc[7] += (w) * _f3.y;           \
    }

template<int LAST>
__global__ __launch_bounds__(256) void hop_kernel(const int* __restrict__ offsets,
                                                  const int2* __restrict__ sedg,
                                                  const __half* __restrict__ Xin,
                                                  const float* __restrict__ W,
                                                  const float* __restrict__ bias,
                                                  __half* __restrict__ Xout,
                                                  float* __restrict__ Fout) {
    __shared__ float As[4][4][68];
    const int t = threadIdx.x;
    const int wid = t >> 6, lane = t & 63;
    const int half = lane >> 5;     // edge slot within a pair
    const int l32 = lane & 31;      // 16B chunk index within the 512B row
    const int node = blockIdx.x * 4 + wid;
    const int s = offsets[node], e = offsets[node + 1];

    float acc[8] = {0.f, 0.f, 0.f, 0.f, 0.f, 0.f, 0.f, 0.f};

    for (int base = s; base < e; base += 64) {
        int cnt = e - base;
        if (cnt > 64) cnt = 64;
        int2 ev = make_int2(0, 0);
        if (lane < cnt) ev = sedg[base + lane];
        const int idxv = ev.x;
        const float wv = __int_as_float(ev.y);
        const int pairs = (cnt + 1) >> 1;
        int p = 0;
        for (; p + 4 <= pairs; p += 4) {
            int   i0 = __shfl(idxv, 2 * p     + half);
            float w0 = __shfl(wv,   2 * p     + half);
            int   i1 = __shfl(idxv, 2 * p + 2 + half);
            float w1 = __shfl(wv,   2 * p + 2 + half);
            int   i2 = __shfl(idxv, 2 * p + 4 + half);
            float w2 = __shfl(wv,   2 * p + 4 + half);
            int   i3 = __shfl(idxv, 2 * p + 6 + half);
            float w3 = __shfl(wv,   2 * p + 6 + half);
            float4 r0 = *(const float4*)(Xin + i0 + l32 * 8);
            float4 r1 = *(const float4*)(Xin + i1 + l32 * 8);
            float4 r2 = *(const float4*)(Xin + i2 + l32 * 8);
            float4 r3 = *(const float4*)(Xin + i3 + l32 * 8);
            ACC8(r0, w0); ACC8(r1, w1); ACC8(r2, w2); ACC8(r3, w3);
        }
        for (; p < pairs; ++p) {
            int   i0 = __shfl(idxv, 2 * p + half);
            float w0 = __shfl(wv,   2 * p + half);
            float4 r0 = *(const float4*)(Xin + i0 + l32 * 8);
            ACC8(r0, w0);
        }
    }

    // combine the two half-wave edge slots
    #pragma unroll
    for (int j = 0; j < 8; ++j) acc[j] += __shfl_xor(acc[j], 32);

    // park agg row in per-wave LDS: element l32*8+j -> (o = l32>>3, k = (l32&7)*8 + j)
    if (half == 0) {
        int o = l32 >> 3, kb = (l32 & 7) * 8;
        *(float4*)&As[wid][o][kb]     = make_float4(acc[0], acc[1], acc[2], acc[3]);
        *(float4*)&As[wid][o][kb + 4] = make_float4(acc[4], acc[5], acc[6], acc[7]);
    }
    __builtin_amdgcn_wave_barrier();   // keep scheduler from moving reads above writes

    // wave-local GEMM: out[o][c4*4+q] = relu(sum_k As[o][k] * W[k][c4*4+q] + b)
    const int o = lane >> 4, c4 = lane & 15;
    float r0 = 0.f, r1 = 0.f, r2 = 0.f, r3 = 0.f;
    #pragma unroll 8
    for (int k = 0; k < 64; ++k) {
        float a = As[wid][o][k];
        float4 wv4 = ((const float4*)(W + k * 64))[c4];
        r0 += a * wv4.x; r1 += a * wv4.y; r2 += a * wv4.z; r3 += a * wv4.w;
    }
    float4 bv = ((const float4*)bias)[c4];
    r0 = fmaxf(r0 + bv.x, 0.f);
    r1 = fmaxf(r1 + bv.y, 0.f);
    r2 = fmaxf(r2 + bv.z, 0.f);
    r3 = fmaxf(r3 + bv.w, 0.f);

    if (LAST) {
        float4 ov = {r0, r1, r2, r3};
        ((float4*)(Fout + (size_t)node * ROW + o * 64))[c4] = ov;
    } else {
        __half2 lo = __float22half2_rn(make_float2(r0, r1));
        __half2 hi = __float22half2_rn(make_float2(r2, r3));
        float2 st;
        *(__half2*)&st.x = lo;
        *(__half2*)&st.y = hi;
        ((float2*)(Xout + (size_t)node * ROW + o * 64))[c4] = st;
    }
}

// ---------------------------------------------------------------- launch
extern "C" void kernel_launch(void* const* d_in, const int* in_sizes, int n_in,
                              void* d_out, int out_size, void* d_ws, size_t ws_size,
                              hipStream_t stream) {
    const float* nodes   = (const float*)d_in[0];
    const int*   esrc    = (const int*)d_in[1];
    const int*   edst    = (const int*)d_in[2];
    const float* eweight = (const float*)d_in[3];
    const float* W_lift  = (const float*)d_in[4];
    const float* b_lift  = (const float*)d_in[5];
    const float* W_hop   = (const float*)d_in[6];
    const float* b_hop   = (const float*)d_in[7];

    char* ws = (char*)d_ws;
    __half* X0  = (__half*)(ws);                       // 25,600,000 B
    __half* X1  = (__half*)(ws + 25600000);            // 25,600,000 B
    int2*  SEDG = (int2*) (ws + 51200000);             //  6,400,000 B
    int*   OFF  = (int*)  (ws + 57600000);             //    200,064 B
    int*   CUR  = (int*)  (ws + 57800064);             //    200,000 B
    int*   CNT  = (int*)  (ws + 58000064);             //    200,000 B
    int*   BSUM = (int*)  (ws + 58200064);             //        256 B

    // CSR build
    zero_kernel<<<(N_NODES + 255) / 256, 256, 0, stream>>>(CNT, N_NODES);
    hist_kernel<<<(N_EDGES + 255) / 256, 256, 0, stream>>>(edst, CNT);
    scan1_kernel<<<NSCAN_BLKS, 1024, 0, stream>>>(CNT, BSUM);
    scan2_kernel<<<1, 64, 0, stream>>>(BSUM);
    scan3_kernel<<<NSCAN_BLKS, 1024, 0, stream>>>(CNT, BSUM, OFF, CUR);
    scatter_kernel<<<(N_EDGES + 255) / 256, 256, 0, stream>>>(esrc, edst, eweight, CUR, SEDG);

    // lift -> f16 X0
    lift_kernel<<<(N_NODES * ROW / 4 + 255) / 256, 256, 0, stream>>>(nodes, W_lift, b_lift, X0);

    // fused hops, double-buffered f16 X
    const int hopGrid = N_NODES / 4;   // 12500 blocks, 4 waves/block, 1 node/wave
    __half* Xi = X0;
    __half* Xo = X1;
    for (int hop = 0; hop < K_HOPS; ++hop) {
        if (hop == K_HOPS - 1) {
            hop_kernel<1><<<hopGrid, 256, 0, stream>>>(OFF, SEDG, Xi, W_hop, b_hop,
                                                       nullptr, (float*)d_out);
        } else {
            hop_kernel<0><<<hopGrid, 256, 0, stream>>>(OFF, SEDG, Xi, W_hop, b_hop,
                                                       Xo, nullptr);
        }
        __half* tmp = Xi; Xi = Xo; Xo = tmp;
    }
}

// Round 4
// 393.679 us; speedup vs baseline: 1.6957x; 1.6957x over previous
//
#include <hip/hip_runtime.h>
#include <hip/hip_fp16.h>

#define N_NODES 50000
#define N_EDGES 800000
#define N_OBS   4
#define HID     64
#define K_HOPS  5
#define ROW     (N_OBS * HID)   // 256 elements per node
#define NSCAN_BLKS ((N_NODES + 1023) / 1024)   // 49

typedef _Float16 f16x8 __attribute__((ext_vector_type(8)));
typedef _Float16 f16x4 __attribute__((ext_vector_type(4)));
typedef float    f32x4 __attribute__((ext_vector_type(4)));

// ---------------------------------------------------------------- zero
__global__ void zero_kernel(int* __restrict__ p, int n) {
    int i = blockIdx.x * blockDim.x + threadIdx.x;
    if (i < n) p[i] = 0;
}

// ---------------------------------------------------------------- histogram of dst
__global__ void hist_kernel(const int* __restrict__ dst, int* __restrict__ cnt) {
    int e = blockIdx.x * blockDim.x + threadIdx.x;
    if (e < N_EDGES) atomicAdd(&cnt[dst[e]], 1);
}

// ---------------------------------------------------------------- scan pass 1: per-block sums
__global__ __launch_bounds__(1024) void scan1_kernel(const int* __restrict__ counts,
                                                     int* __restrict__ bsum) {
    __shared__ int wsum[16];
    const int t = threadIdx.x, lane = t & 63, wid = t >> 6;
    int i = blockIdx.x * 1024 + t;
    int x = (i < N_NODES) ? counts[i] : 0;
    #pragma unroll
    for (int off = 32; off > 0; off >>= 1) x += __shfl_xor(x, off);
    if (lane == 0) wsum[wid] = x;
    __syncthreads();
    if (t == 0) {
        int s = 0;
        #pragma unroll
        for (int j = 0; j < 16; ++j) s += wsum[j];
        bsum[blockIdx.x] = s;
    }
}

// ---------------------------------------------------------------- scan pass 2: exclusive scan of block sums (1 wave)
__global__ void scan2_kernel(int* __restrict__ bsum) {
    const int t = threadIdx.x;   // 64 threads
    int v = (t < NSCAN_BLKS) ? bsum[t] : 0;
    int x = v;
    #pragma unroll
    for (int off = 1; off < 64; off <<= 1) {
        int y = __shfl_up(x, off);
        if (t >= off) x += y;
    }
    if (t < NSCAN_BLKS) bsum[t] = x - v;   // exclusive
}

// ---------------------------------------------------------------- scan pass 3: full offsets + cursor
__global__ __launch_bounds__(1024) void scan3_kernel(const int* __restrict__ counts,
                                                     const int* __restrict__ bsum,
                                                     int* __restrict__ offsets,
                                                     int* __restrict__ cursor) {
    __shared__ int wsum[16];
    __shared__ int wpre[16];
    const int t = threadIdx.x, lane = t & 63, wid = t >> 6;
    int i = blockIdx.x * 1024 + t;
    int v = (i < N_NODES) ? counts[i] : 0;
    int x = v;
    #pragma unroll
    for (int off = 1; off < 64; off <<= 1) {
        int y = __shfl_up(x, off);
        if (lane >= off) x += y;
    }
    if (lane == 63) wsum[wid] = x;
    __syncthreads();
    if (t < 16) {
        int p = 0;
        for (int j = 0; j < t; ++j) p += wsum[j];
        wpre[t] = p;
    }
    __syncthreads();
    int base = bsum[blockIdx.x];
    int incl = base + x + wpre[wid];
    if (i < N_NODES) {
        offsets[i + 1] = incl;
        cursor[i]      = incl - v;
    }
    if (i == 0) offsets[0] = 0;
}

// ---------------------------------------------------------------- scatter edges into CSR order (packed {src*ROW, w})
__global__ void scatter_kernel(const int* __restrict__ src, const int* __restrict__ dst,
                               const float* __restrict__ w, int* __restrict__ cursor,
                               int2* __restrict__ sedg) {
    int e = blockIdx.x * blockDim.x + threadIdx.x;
    if (e < N_EDGES) {
        int d = dst[e];
        int p = atomicAdd(&cursor[d], 1);
        sedg[p] = make_int2(src[e] * ROW, __float_as_int(w[e]));
    }
}

// ---------------------------------------------------------------- lift: X[n,o,h] = f16(nodes[n,o]*Wl[h] + bl[h])
__global__ void lift_kernel(const float* __restrict__ nodes, const float* __restrict__ Wl,
                            const float* __restrict__ bl, __half* __restrict__ X) {
    int i = blockIdx.x * blockDim.x + threadIdx.x;
    const int total = N_NODES * ROW / 4;
    if (i >= total) return;
    int h4 = i & 15;
    int no = i >> 4;
    float s = nodes[no];
    float4 wl = ((const float4*)Wl)[h4];
    float4 b  = ((const float4*)bl)[h4];
    __half2 lo = __float22half2_rn(make_float2(s * wl.x + b.x, s * wl.y + b.y));
    __half2 hi = __float22half2_rn(make_float2(s * wl.z + b.z, s * wl.w + b.w));
    float2 st;
    *(__half2*)&st.x = lo;
    *(__half2*)&st.y = hi;
    ((float2*)X)[i] = st;
}

// ---------------------------------------------------------------- pack W_hop into MFMA B-fragment order (f16)
// Bp[w][ks][lane][j] = W[k][col], k = ks*32 + 16*(j>>2) + 4*(lane>>4) + (j&3),
// col = w*16 + (lane&15).  (x32 MFMA = two stacked x16 fragments.)
__global__ void packW_kernel(const float* __restrict__ W, _Float16* __restrict__ Bp) {
    int i = blockIdx.x * 256 + threadIdx.x;   // 0..4095
    if (i >= 4096) return;
    int j  = i & 7;
    int l  = (i >> 3) & 63;
    int ks = (i >> 9) & 1;
    int w  = i >> 10;
    int k   = ks * 32 + ((j >> 2) * 16) + ((l >> 4) * 4) + (j & 3);
    int col = w * 16 + (l & 15);
    Bp[i] = (_Float16)W[k * 64 + col];
}

// ---------------------------------------------------------------- fused hop:
// 4 waves/block, 1 dst node/wave. Gather: edge chunk preload + shfl broadcast,
// 2 edges per 16B/lane load, depth-8 pipelined (weight-zero padded).
// Agg parked as f16 in LDS (16x64 panel); per-wave 16x16 output tile via
// 2x mfma_f32_16x16x32_f16; bias+ReLU fused; coalesced stores.
#define ACC8(r, w)                                              \
    {                                                           \
        __half2* _h = (__half2*)&(r);                           \
        float2 _f0 = __half22float2(_h[0]);                     \
        float2 _f1 = __half22float2(_h[1]);                     \
        float2 _f2 = __half22float2(_h[2]);                     \
        float2 _f3 = __half22float2(_h[3]);                     \
        acc[0] += (w) * _f0.x; acc[1] += (w) * _f0.y;           \
        acc[2] += (w) * _f1.x; acc[3] += (w) * _f1.y;           \
        acc[4] += (w) * _f2.x; acc[5] += (w) * _f2.y;           \
        acc[6] += (w) * _f3.x; acc[7] += (w) * _f3.y;           \
    }

template<int LAST>
__global__ __launch_bounds__(256) void hop_kernel(const int* __restrict__ offsets,
                                                  const int2* __restrict__ sedg,
                                                  const __half* __restrict__ Xin,
                                                  const _Float16* __restrict__ Bp,
                                                  const float* __restrict__ bias,
                                                  __half* __restrict__ Xout,
                                                  float* __restrict__ Fout) {
    __shared__ _Float16 As16[16][72];   // 16 rows (4 nodes x 4 obs) x 64 + pad
    const int t = threadIdx.x;
    const int wid = t >> 6, lane = t & 63;
    const int half = lane >> 5;     // edge slot within a pair
    const int l32 = lane & 31;      // 16B chunk index within the 512B row
    const int node = blockIdx.x * 4 + wid;
    const int s = offsets[node], e = offsets[node + 1];

    float acc[8] = {0.f, 0.f, 0.f, 0.f, 0.f, 0.f, 0.f, 0.f};

    for (int base = s; base < e; base += 64) {
        int cnt = e - base;
        if (cnt > 64) cnt = 64;
        int2 ev = make_int2(0, 0);            // idx 0, weight 0 for pad lanes
        if (lane < cnt) ev = sedg[base + lane];
        const int idxv = ev.x;
        const float wv = __int_as_float(ev.y);
        int pairs  = (cnt + 1) >> 1;
        int pairs8 = (pairs + 7) & ~7;        // pad to 8: extra pairs have w=0
        for (int pb = 0; pb < pairs8; pb += 8) {
            float4 r[8];
            float  w[8];
            #pragma unroll
            for (int q = 0; q < 8; ++q) {
                int sl = 2 * (pb + q) + half;
                int   i_ = __shfl(idxv, sl);
                w[q]     = __shfl(wv,   sl);
                r[q] = *(const float4*)(Xin + i_ + l32 * 8);
            }
            #pragma unroll
            for (int q = 0; q < 8; ++q) ACC8(r[q], w[q]);
        }
    }

    // combine the two half-wave edge slots
    #pragma unroll
    for (int j = 0; j < 8; ++j) acc[j] += __shfl_xor(acc[j], 32);

    // park agg row as f16: element l32*8+j -> (o = l32>>3, k = (l32&7)*8 + j)
    if (half == 0) {
        int o = l32 >> 3, kb = (l32 & 7) * 8;
        __half2 p0 = __float22half2_rn(make_float2(acc[0], acc[1]));
        __half2 p1 = __float22half2_rn(make_float2(acc[2], acc[3]));
        __half2 p2 = __float22half2_rn(make_float2(acc[4], acc[5]));
        __half2 p3 = __float22half2_rn(make_float2(acc[6], acc[7]));
        float4 st;
        ((__half2*)&st)[0] = p0; ((__half2*)&st)[1] = p1;
        ((__half2*)&st)[2] = p2; ((__half2*)&st)[3] = p3;
        *(float4*)&As16[wid * 4 + o][kb] = st;
    }
    __syncthreads();

    // per-wave 16x16 output tile: rows = 16 agg rows, cols = wid*16..+15
    const int r15 = lane & 15;    // A-row for frag load; C/D col in epilogue
    const int g   = lane >> 4;    // k-group for frags; C/D row-group (= local node)
    f16x8 a0, a1;
    ((f16x4*)&a0)[0] = *(const f16x4*)&As16[r15][ 0 + 4 * g];
    ((f16x4*)&a0)[1] = *(const f16x4*)&As16[r15][16 + 4 * g];
    ((f16x4*)&a1)[0] = *(const f16x4*)&As16[r15][32 + 4 * g];
    ((f16x4*)&a1)[1] = *(const f16x4*)&As16[r15][48 + 4 * g];
    f16x8 b0 = *(const f16x8*)(Bp + ((size_t)(wid * 2 + 0) * 64 + lane) * 8);
    f16x8 b1 = *(const f16x8*)(Bp + ((size_t)(wid * 2 + 1) * 64 + lane) * 8);
    f32x4 c = {0.f, 0.f, 0.f, 0.f};
    c = __builtin_amdgcn_mfma_f32_16x16x32_f16(a0, b0, c, 0, 0, 0);
    c = __builtin_amdgcn_mfma_f32_16x16x32_f16(a1, b1, c, 0, 0, 0);

    const float bv = bias[wid * 16 + r15];
    const size_t obase = (size_t)(blockIdx.x * 4 + g) * ROW + wid * 16 + r15;
    #pragma unroll
    for (int j = 0; j < 4; ++j) {           // j = obs index (C/D row within group)
        float v = fmaxf(c[j] + bv, 0.f);
        if (LAST) Fout[obase + j * 64] = v;
        else      Xout[obase + j * 64] = __float2half(v);
    }
}

// ---------------------------------------------------------------- launch
extern "C" void kernel_launch(void* const* d_in, const int* in_sizes, int n_in,
                              void* d_out, int out_size, void* d_ws, size_t ws_size,
                              hipStream_t stream) {
    const float* nodes   = (const float*)d_in[0];
    const int*   esrc    = (const int*)d_in[1];
    const int*   edst    = (const int*)d_in[2];
    const float* eweight = (const float*)d_in[3];
    const float* W_lift  = (const float*)d_in[4];
    const float* b_lift  = (const float*)d_in[5];
    const float* W_hop   = (const float*)d_in[6];
    const float* b_hop   = (const float*)d_in[7];

    char* ws = (char*)d_ws;
    __half*    X0   = (__half*)(ws);                   // 25,600,000 B
    __half*    X1   = (__half*)(ws + 25600000);        // 25,600,000 B
    int2*      SEDG = (int2*) (ws + 51200000);         //  6,400,000 B
    int*       OFF  = (int*)  (ws + 57600000);         //    200,064 B
    int*       CUR  = (int*)  (ws + 57800064);         //    200,000 B
    int*       CNT  = (int*)  (ws + 58000064);         //    200,000 B
    int*       BSUM = (int*)  (ws + 58200064);         //        256 B
    _Float16*  BP   = (_Float16*)(ws + 58200320);      //      8,192 B

    // CSR build
    zero_kernel<<<(N_NODES + 255) / 256, 256, 0, stream>>>(CNT, N_NODES);
    hist_kernel<<<(N_EDGES + 255) / 256, 256, 0, stream>>>(edst, CNT);
    scan1_kernel<<<NSCAN_BLKS, 1024, 0, stream>>>(CNT, BSUM);
    scan2_kernel<<<1, 64, 0, stream>>>(BSUM);
    scan3_kernel<<<NSCAN_BLKS, 1024, 0, stream>>>(CNT, BSUM, OFF, CUR);
    scatter_kernel<<<(N_EDGES + 255) / 256, 256, 0, stream>>>(esrc, edst, eweight, CUR, SEDG);

    // lift -> f16 X0 ; pack W_hop -> MFMA B fragments
    lift_kernel<<<(N_NODES * ROW / 4 + 255) / 256, 256, 0, stream>>>(nodes, W_lift, b_lift, X0);
    packW_kernel<<<16, 256, 0, stream>>>(W_hop, BP);

    // fused hops, double-buffered f16 X
    const int hopGrid = N_NODES / 4;   // 12500 blocks, 4 waves/block, 1 node/wave
    __half* Xi = X0;
    __half* Xo = X1;
    for (int hop = 0; hop < K_HOPS; ++hop) {
        if (hop == K_HOPS - 1) {
            hop_kernel<1><<<hopGrid, 256, 0, stream>>>(OFF, SEDG, Xi, BP, b_hop,
                                                       nullptr, (float*)d_out);
        } else {
            hop_kernel<0><<<hopGrid, 256, 0, stream>>>(OFF, SEDG, Xi, BP, b_hop,
                                                       Xo, nullptr);
        }
        __half* tmp = Xi; Xi = Xo; Xo = tmp;
    }
}